// Round 2
// baseline (668.432 us; speedup 1.0000x reference)
//
#include <hip/hip_runtime.h>

// MultiFeatureMOE: F=4, E=8, B=4096, D=512, H=1024, O=512.
// Round 9 (= round 8 resubmit + conflict-free swizzle): ring-buffered
// deep-prefetch GEMM schedule replacing the m97-style 2-barrier K-loop:
//   - BK=32, 4 LDS slots; compute tile kt from slot kt%4 while staging tile
//     kt+3 into the slot freed after tile kt-1 (race-free: stage loads issue
//     only after the barrier ending that slot's last reader).
//   - raw s_barrier + counted s_waitcnt vmcnt(8/6) once per K-tile, NEVER 0 in
//     steady state (tail: 8/6 -> 4/3 -> 0). Loads stay in flight across barriers.
//   - s_setprio(1) around 16-MFMA clusters.
//   - chunk swizzle f(row) = (row + row/4) & 3 on BOTH the staging source and
//     the ds_read address (global_load_lds dests stay linear). Read side
//     collapses to lane constant (lr + lr/4)&3 -> 2 lanes/bank = conflict-free
//     ds_read_b128 (old row&3 scheme was 4-way conflicted).
// gemm1: 256x256 tile, 8 waves (2Mx4N, wave 128x64). grid 512/f (2 rounds).
// gemm2: 256x128 tile, 8 waves (4Mx2N, wave 64x64), 2 experts/block (K=2048).
//        grid 256/f (1 exact round). part stays 16 bf16 slabs -> reduce unchanged.

#define F_ 4
#define E_ 8
#define B_ 4096
#define D_ 512
#define H_ 1024
#define O_ 512

typedef unsigned short ushort_t;
typedef __bf16 bf16x8 __attribute__((ext_vector_type(8)));
typedef float f32x4 __attribute__((ext_vector_type(4)));
typedef unsigned short ushort8_t __attribute__((ext_vector_type(8)));

__device__ inline ushort_t f2bf(float f) {
  union { float f; unsigned u; } v; v.f = f;
  unsigned r = v.u + 0x7FFFu + ((v.u >> 16) & 1u);  // RNE
  return (ushort_t)(r >> 16);
}
__device__ inline float bf2f(ushort_t u) {
  union { unsigned u; float f; } v; v.u = ((unsigned)u) << 16;
  return v.f;
}

__device__ inline void async16(const void* g, void* l) {
  __builtin_amdgcn_global_load_lds(
      (const __attribute__((address_space(1))) unsigned int*)g,
      (__attribute__((address_space(3))) unsigned int*)l, 16, 0, 0);
}

// raw barrier, fenced so plain LDS reads cannot migrate across slot reuse
__device__ inline void barrier_() {
  __builtin_amdgcn_sched_barrier(0);
  asm volatile("" ::: "memory");
  __builtin_amdgcn_s_barrier();
  asm volatile("" ::: "memory");
  __builtin_amdgcn_sched_barrier(0);
}

// ---------------- prep: gate softmax (fp32) + feature bf16 cast, fused ----------------
__global__ void prep_kernel(const float* __restrict__ features, const float* __restrict__ Wg,
                            const float* __restrict__ bg, float* __restrict__ g2,
                            ushort_t* __restrict__ featbf) {
  const int fb = blockIdx.x;
  const int f = fb >> 12, b = fb & (B_ - 1);
  const int lane = threadIdx.x;
  const float* feat = features + ((size_t)f * B_ + b) * D_;
  const float* wg = Wg + (size_t)f * D_ * E_;
  const int d0 = lane * 8;
  float ff[8];
  *(float4*)&ff[0] = *(const float4*)&feat[d0];
  *(float4*)&ff[4] = *(const float4*)&feat[d0 + 4];
  ushort8_t u;
#pragma unroll
  for (int k = 0; k < 8; ++k) u[k] = f2bf(ff[k]);
  *(ushort8_t*)&featbf[((size_t)f * B_ + b) * D_ + d0] = u;

  float acc[E_] = {0.f, 0.f, 0.f, 0.f, 0.f, 0.f, 0.f, 0.f};
#pragma unroll
  for (int k = 0; k < 8; ++k) {
    const float fv = ff[k];
    const float4 w0 = ((const float4*)(wg + (size_t)(d0 + k) * E_))[0];
    const float4 w1 = ((const float4*)(wg + (size_t)(d0 + k) * E_))[1];
    acc[0] += fv * w0.x; acc[1] += fv * w0.y; acc[2] += fv * w0.z; acc[3] += fv * w0.w;
    acc[4] += fv * w1.x; acc[5] += fv * w1.y; acc[6] += fv * w1.z; acc[7] += fv * w1.w;
  }
#pragma unroll
  for (int off = 32; off >= 1; off >>= 1)
#pragma unroll
    for (int e = 0; e < E_; ++e) acc[e] += __shfl_xor(acc[e], off, 64);
  float lg[E_], mx = -1e30f;
#pragma unroll
  for (int e = 0; e < E_; ++e) { lg[e] = acc[e] + bg[f * E_ + e]; mx = fmaxf(mx, lg[e]); }
  float s = 0.f;
#pragma unroll
  for (int e = 0; e < E_; ++e) { lg[e] = __expf(lg[e] - mx); s += lg[e]; }
  const float inv = 1.f / (s * (float)F_);
  if (lane < E_) g2[((size_t)f * B_ + b) * E_ + lane] = lg[lane] * inv;
}

// ------------- batched transpose+cast: [R][C] fp32 -> [C][R] bf16 -------------
__global__ void transpose_cast_kernel(const float* __restrict__ in, ushort_t* __restrict__ out,
                                      int R, int C) {
  __shared__ float tile[64][65];
  const size_t zoff = (size_t)blockIdx.z * R * C;
  in += zoff; out += zoff;
  const int tx = threadIdx.x & 63, ty = threadIdx.x >> 6;
  const int r0 = blockIdx.y * 64, c0 = blockIdx.x * 64;
#pragma unroll
  for (int i = 0; i < 16; ++i) {
    const int r = ty + i * 4;
    tile[r][tx] = in[(size_t)(r0 + r) * C + c0 + tx];
  }
  __syncthreads();
#pragma unroll
  for (int i = 0; i < 16; ++i) {
    const int c = ty + i * 4;
    out[(size_t)(c0 + c) * R + r0 + tx] = f2bf(tile[tx][c]);
  }
}

// =========================== GEMM1: 256x256, BK=32, 4-slot ring ===========================
// LDS slot (32KB): A[256][32] @ 0, B[256][32] @ 8192 (ushorts). 4 slots = 128KB.
// Staging: thread t covers row rr=t>>2 (+128 for p=1), phys chunk t&3, source
// chunk (t&3)^fsw(rr) (fsw p-invariant: fsw(r+128)==fsw(r)). Reads: phys chunk
// q^fsw(row); for rows R0+lr (R0%16==0) this is the lane constant q^((lr+lr/4)&3).
// acc[I][j]: m = wm*128 + (I>>2)*64 + (I&3)*16 + lr ; n = wn*64 + j*16 + q*4 + {0..3}.

#define FSW(r) (((r) + ((r) >> 2)) & 3)

#define G1_VM8 asm volatile("s_waitcnt vmcnt(8)" ::: "memory")
#define G1_VM4 asm volatile("s_waitcnt vmcnt(4)" ::: "memory")
#define G1_VM0 asm volatile("s_waitcnt vmcnt(0)" ::: "memory")
#define G_NOP ((void)0)

#define STAGE1(ktn, p) { \
    ushort_t* s_ = &lds[((ktn) & 3) * 16384]; \
    async16(aG + (ktn) * 32 + (p) * (128 * D_), s_ + (p) * 4096 + t * 8); \
    async16(bG + (ktn) * 32 + (p) * (128 * D_), s_ + 8192 + (p) * 4096 + t * 8); }

#define G1_TILE(kt, STG, VMS) { \
    const int sl = ((kt) & 3) * 16384; \
    bf16x8 bfr[4]; \
    _Pragma("unroll") for (int j = 0; j < 4; ++j) \
      bfr[j] = *(const bf16x8*)&lds[sl + 8192 + (wn * 64 + j * 16 + lr) * 32 + ca]; \
    { bf16x8 af[4]; \
      _Pragma("unroll") for (int i = 0; i < 4; ++i) \
        af[i] = *(const bf16x8*)&lds[sl + (wm * 128 + i * 16 + lr) * 32 + ca]; \
      if (STG) { STAGE1((kt) + 3, 0); } \
      __builtin_amdgcn_s_setprio(1); \
      _Pragma("unroll") for (int i = 0; i < 4; ++i) \
        _Pragma("unroll") for (int j = 0; j < 4; ++j) \
          acc[i][j] = __builtin_amdgcn_mfma_f32_16x16x32_bf16(bfr[j], af[i], acc[i][j], 0, 0, 0); \
      __builtin_amdgcn_s_setprio(0); \
      barrier_(); } \
    { bf16x8 af[4]; \
      _Pragma("unroll") for (int i = 0; i < 4; ++i) \
        af[i] = *(const bf16x8*)&lds[sl + (wm * 128 + 64 + i * 16 + lr) * 32 + ca]; \
      if (STG) { STAGE1((kt) + 3, 1); } \
      __builtin_amdgcn_s_setprio(1); \
      _Pragma("unroll") for (int i = 0; i < 4; ++i) \
        _Pragma("unroll") for (int j = 0; j < 4; ++j) \
          acc[4 + i][j] = __builtin_amdgcn_mfma_f32_16x16x32_bf16(bfr[j], af[i], acc[4 + i][j], 0, 0, 0); \
      __builtin_amdgcn_s_setprio(0); \
      VMS; \
      barrier_(); } }

__global__ __launch_bounds__(512, 2) void gemm1_kernel(
    const ushort_t* __restrict__ featbf, const ushort_t* __restrict__ w1t,
    const float* __restrict__ b1, const float* __restrict__ g2,
    ushort_t* __restrict__ Hf, int f) {
  __shared__ __align__(16) ushort_t lds[65536];  // 128 KB
  const int id = blockIdx.x;
  const int e = id & 7;
  const int s = id >> 3;          // 0..63
  const int n0 = (s & 3) * 256;   // h
  const int m0 = (s >> 2) * 256;  // b
  const ushort_t* A  = featbf + (size_t)f * B_ * D_;
  const ushort_t* Bp = w1t + ((size_t)f * E_ + e) * (size_t)H_ * D_;
  const float* b1e = b1 + ((size_t)f * E_ + e) * H_;
  const float* g2f = g2 + (size_t)f * B_ * E_;
  ushort_t* HfE = Hf + (size_t)e * B_ * H_;

  const int t = threadIdx.x, lane = t & 63, w = t >> 6;
  const int wm = w >> 2, wn = w & 3;        // wm 0..1, wn 0..3
  const int lr = lane & 15, q = lane >> 4;  // q 0..3
  const int ca = (q ^ FSW(lr)) * 8;         // read-side swizzle (lane constant)

  const int rr = t >> 2;                    // 0..127
  const int cc = (t & 3) ^ FSW(rr);         // staging source chunk
  const ushort_t* aG = A  + (size_t)(m0 + rr) * D_ + cc * 8;
  const ushort_t* bG = Bp + (size_t)(n0 + rr) * D_ + cc * 8;

  f32x4 acc[8][4];
#pragma unroll
  for (int i = 0; i < 8; ++i)
#pragma unroll
    for (int j = 0; j < 4; ++j) acc[i][j] = (f32x4){0.f, 0.f, 0.f, 0.f};

  // prologue: stage tiles 0,1,2 (12 loads); tile0 ready when <=8 outstanding
  STAGE1(0, 0); STAGE1(0, 1);
  STAGE1(1, 0); STAGE1(1, 1);
  STAGE1(2, 0); STAGE1(2, 1);
  G1_VM8;
  barrier_();

  // KT = 16 K-tiles (D=512 / 32). Main: stage kt+3; tail vmcnt 8->4->0.
#pragma unroll 4
  for (int kt = 0; kt < 12; ++kt) G1_TILE(kt, true, G1_VM8);
  G1_TILE(12, true, G1_VM8);
  G1_TILE(13, false, G1_VM4);
  G1_TILE(14, false, G1_VM0);
  G1_TILE(15, false, G_NOP);

  // epilogue: bias+relu+gate -> LDS [128][264] per M-half -> coalesced stores
  ushort_t* cb = lds;
#pragma unroll
  for (int mh = 0; mh < 2; ++mh) {
    if (wm == mh) {
#pragma unroll
      for (int I = 0; I < 8; ++I) {
        const int rl = (I >> 2) * 64 + (I & 3) * 16 + lr;  // 0..127
        const float gv = g2f[(size_t)(m0 + mh * 128 + rl) * E_ + e];
#pragma unroll
        for (int j = 0; j < 4; ++j) {
          const int nl = wn * 64 + j * 16 + q * 4;
          const float4 bb = *(const float4*)&b1e[n0 + nl];
          ushort4 o;
          o.x = f2bf(fmaxf(acc[I][j][0] + bb.x, 0.f) * gv);
          o.y = f2bf(fmaxf(acc[I][j][1] + bb.y, 0.f) * gv);
          o.z = f2bf(fmaxf(acc[I][j][2] + bb.z, 0.f) * gv);
          o.w = f2bf(fmaxf(acc[I][j][3] + bb.w, 0.f) * gv);
          *(ushort4*)&cb[rl * 264 + nl] = o;
        }
      }
    }
    __syncthreads();
    const int row = t >> 2, seg = t & 3;
    const ushort_t* src = &cb[row * 264 + seg * 64];
    ushort_t* dst = HfE + (size_t)(m0 + mh * 128 + row) * H_ + n0 + seg * 64;
#pragma unroll
    for (int c = 0; c < 8; ++c)
      *(ushort8_t*)(dst + c * 8) = *(const ushort8_t*)(src + c * 8);
    __syncthreads();
  }
}

// =========================== GEMM2: 256x128, BK=32, 4-slot ring ===========================
// LDS slot (24KB): A[256][32] @ 0, B[128][32] @ 8192 (ushorts). 4 slots = 96KB.
// 2 experts per block (K = 2*1024 -> 64 K-tiles). 3 loads/thread/tile -> vmcnt(6).

#define G2_VM6 asm volatile("s_waitcnt vmcnt(6)" ::: "memory")
#define G2_VM3 asm volatile("s_waitcnt vmcnt(3)" ::: "memory")
#define G2_VM0 asm volatile("s_waitcnt vmcnt(0)" ::: "memory")

#define STAGE2(ktn) { \
    ushort_t* s_ = &lds[((ktn) & 3) * 12288]; \
    const ushort_t* ag = Hf + (size_t)(e0 + ((ktn) >> 5)) * ((size_t)B_ * H_) + aOff + ((ktn) & 31) * 32; \
    const ushort_t* bgp = w2tF + (size_t)(e0 + ((ktn) >> 5)) * ((size_t)O_ * H_) + bOff + ((ktn) & 31) * 32; \
    async16(ag, s_ + t * 8); \
    async16(ag + 128 * H_, s_ + 4096 + t * 8); \
    async16(bgp, s_ + 8192 + t * 8); }

#define G2_TILE(kt, STG, VMS) { \
    const int sl = ((kt) & 3) * 12288; \
    bf16x8 bfr[4], af[4]; \
    _Pragma("unroll") for (int j = 0; j < 4; ++j) \
      bfr[j] = *(const bf16x8*)&lds[sl + 8192 + (wn * 64 + j * 16 + lr) * 32 + ca]; \
    _Pragma("unroll") for (int i = 0; i < 4; ++i) \
      af[i] = *(const bf16x8*)&lds[sl + (wm * 64 + i * 16 + lr) * 32 + ca]; \
    if (STG) { STAGE2((kt) + 3); } \
    __builtin_amdgcn_s_setprio(1); \
    _Pragma("unroll") for (int i = 0; i < 4; ++i) \
      _Pragma("unroll") for (int j = 0; j < 4; ++j) \
        acc[i][j] = __builtin_amdgcn_mfma_f32_16x16x32_bf16(bfr[j], af[i], acc[i][j], 0, 0, 0); \
    __builtin_amdgcn_s_setprio(0); \
    VMS; \
    barrier_(); }

__global__ __launch_bounds__(512, 2) void gemm2_kernel(
    const ushort_t* __restrict__ Hf, const ushort_t* __restrict__ w2t,
    const float* __restrict__ b2, const float* __restrict__ g2,
    ushort_t* __restrict__ part, int f) {
  __shared__ __align__(16) ushort_t lds[49152];  // 96 KB
  const int id = blockIdx.x;      // 0..255
  const int grp = id & 3;
  const int s = id >> 2;          // 0..63
  const int n0 = (s & 3) * 128;   // o
  const int m0 = (s >> 2) * 256;  // b
  const int e0 = grp * 2;
  const ushort_t* w2tF = w2t + (size_t)f * E_ * O_ * H_;
  const float* g2f = g2 + (size_t)f * B_ * E_;

  const int t = threadIdx.x, lane = t & 63, w = t >> 6;
  const int wm = w >> 1, wn = w & 1;        // wm 0..3, wn 0..1
  const int lr = lane & 15, q = lane >> 4;
  const int ca = (q ^ FSW(lr)) * 8;

  const int rr = t >> 2;                    // 0..127
  const int cc = (t & 3) ^ FSW(rr);
  const size_t aOff = (size_t)(m0 + rr) * H_ + cc * 8;
  const size_t bOff = (size_t)(n0 + rr) * H_ + cc * 8;

  f32x4 acc[4][4];
#pragma unroll
  for (int i = 0; i < 4; ++i)
#pragma unroll
    for (int j = 0; j < 4; ++j) acc[i][j] = (f32x4){0.f, 0.f, 0.f, 0.f};

  // prologue: stage tiles 0,1,2 (9 loads); tile0 ready when <=6 outstanding
  STAGE2(0); STAGE2(1); STAGE2(2);
  G2_VM6;
  barrier_();

  // KT = 64 (2 experts x H/32). Main: stage kt+3; tail vmcnt 6->3->0.
#pragma unroll 4
  for (int kt = 0; kt < 60; ++kt) G2_TILE(kt, true, G2_VM6);
  G2_TILE(60, true, G2_VM6);
  G2_TILE(61, false, G2_VM3);
  G2_TILE(62, false, G2_VM0);
  G2_TILE(63, false, G_NOP);

  // epilogue: acc + g*b2 -> LDS [256][136] -> coalesced stores
  ushort_t* cb = lds;
  const float* b2e0 = b2 + ((size_t)f * E_ + e0) * O_;
  const float* b2e1 = b2e0 + O_;
#pragma unroll
  for (int i = 0; i < 4; ++i) {
    const int ml = wm * 64 + i * 16 + lr;
    const float gv0 = g2f[(size_t)(m0 + ml) * E_ + e0];
    const float gv1 = g2f[(size_t)(m0 + ml) * E_ + e0 + 1];
#pragma unroll
    for (int j = 0; j < 4; ++j) {
      const int nl = wn * 64 + j * 16 + q * 4;
      const int n = n0 + nl;
      const float4 c0 = *(const float4*)&b2e0[n];
      const float4 c1 = *(const float4*)&b2e1[n];
      ushort4 o;
      o.x = f2bf(acc[i][j][0] + gv0 * c0.x + gv1 * c1.x);
      o.y = f2bf(acc[i][j][1] + gv0 * c0.y + gv1 * c1.y);
      o.z = f2bf(acc[i][j][2] + gv0 * c0.z + gv1 * c1.z);
      o.w = f2bf(acc[i][j][3] + gv0 * c0.w + gv1 * c1.w);
      *(ushort4*)&cb[ml * 136 + nl] = o;
    }
  }
  __syncthreads();
  const int row = t >> 1, half = t & 1;
  const ushort_t* src = &cb[row * 136 + half * 64];
  ushort_t* dst = part + (size_t)(f * 4 + grp) * (B_ * O_) + (size_t)(m0 + row) * O_ + n0 + half * 64;
#pragma unroll
  for (int c = 0; c < 8; ++c)
    *(ushort8_t*)(dst + c * 8) = *(const ushort8_t*)(src + c * 8);
}

// ---------------- final reduce: out = sum over 16 bf16 slabs ----------------
__global__ void reduce_kernel(const ushort_t* __restrict__ part, float* __restrict__ out) {
  const size_t p = ((size_t)blockIdx.x * 256 + threadIdx.x) * 8;
  float s[8] = {0.f, 0.f, 0.f, 0.f, 0.f, 0.f, 0.f, 0.f};
#pragma unroll
  for (int k = 0; k < F_ * 4; ++k) {
    const ushort8_t u = *(const ushort8_t*)&part[(size_t)k * (B_ * O_) + p];
#pragma unroll
    for (int j = 0; j < 8; ++j) s[j] += bf2f(u[j]);
  }
  float4 o0 = {s[0], s[1], s[2], s[3]}, o1 = {s[4], s[5], s[6], s[7]};
  *(float4*)&out[p] = o0;
  *(float4*)&out[p + 4] = o1;
}

extern "C" void kernel_launch(void* const* d_in, const int* in_sizes, int n_in,
                              void* d_out, int out_size, void* d_ws, size_t ws_size,
                              hipStream_t stream) {
  const float* features = (const float*)d_in[0];
  const float* W1 = (const float*)d_in[1];
  const float* b1 = (const float*)d_in[2];
  const float* W2 = (const float*)d_in[3];
  const float* b2 = (const float*)d_in[4];
  const float* Wg = (const float*)d_in[5];
  const float* bg = (const float*)d_in[6];
  float* out = (float*)d_out;

  char* ws = (char*)d_ws;
  ushort_t* featbf = (ushort_t*)ws;                  // 16 MB   [F][B][D]
  ushort_t* w1t    = (ushort_t*)(ws + 16777216);     // 32 MB   [F][E][H][D]
  ushort_t* w2t    = (ushort_t*)(ws + 50331648);     // 32 MB   [F][E][O][H]
  float*    g2     = (float*)(ws + 83886080);        // 0.5 MB  [F][B][E]
  ushort_t* Hf     = (ushort_t*)(ws + 84410368);     // 64 MB   [E][B][H] (per-f)
  ushort_t* part   = (ushort_t*)(ws + 151519232);    // 64 MB   [F*4][B][O] bf16

  prep_kernel<<<F_ * B_, 64, 0, stream>>>(features, Wg, bg, g2, featbf);
  transpose_cast_kernel<<<dim3(H_ / 64, D_ / 64, F_ * E_), 256, 0, stream>>>(W1, w1t, D_, H_);
  transpose_cast_kernel<<<dim3(O_ / 64, H_ / 64, F_ * E_), 256, 0, stream>>>(W2, w2t, H_, O_);

  for (int f = 0; f < F_; ++f) {
    gemm1_kernel<<<512, 512, 0, stream>>>(featbf, w1t, b1, g2, Hf, f);
    gemm2_kernel<<<256, 512, 0, stream>>>(Hf, w2t, b2, g2, part, f);
  }
  reduce_kernel<<<B_ * O_ / 8 / 256, 256, 0, stream>>>(part, out);
}

// Round 3
// 657.857 us; speedup vs baseline: 1.0161x; 1.0161x over previous
//
#include <hip/hip_runtime.h>

// MultiFeatureMOE: F=4, E=8, B=4096, D=512, H=1024, O=512.
// Round 10: differential test of the LDS-DMA aliasing-drain theory.
// Round-2 failure diagnosed as: hipcc inserts s_waitcnt vmcnt(0) before PLAIN
// ds_reads that may alias outstanding global_load_lds writes (SIInsertWaitcnts
// LDS-DMA tracking) -> every phase waited on just-issued prefetches.
// Fix: K-loop LDS reads via inline-asm ds_read_b128 (opaque to the pass),
// explicit lgkmcnt(0)+sched_barrier(0) (rule 18), raw s_barrier, counted
// s_waitcnt vmcnt(8) once per step (tail 8->4->0). Geometry restored to the
// proven 128x128 tile / 4 waves / 2048 blocks, 3-slot BK=32 ring (48 KB LDS,
// 3 blocks/CU). Swizzle f(r)=(r+r/4)&3 on staging source + read side keeps
// ds_read_b128 conflict-free with linear DMA destinations.

#define F_ 4
#define E_ 8
#define B_ 4096
#define D_ 512
#define H_ 1024
#define O_ 512

typedef unsigned short ushort_t;
typedef __bf16 bf16x8 __attribute__((ext_vector_type(8)));
typedef float f32x4 __attribute__((ext_vector_type(4)));
typedef unsigned short ushort8_t __attribute__((ext_vector_type(8)));

__device__ inline ushort_t f2bf(float f) {
  union { float f; unsigned u; } v; v.f = f;
  unsigned r = v.u + 0x7FFFu + ((v.u >> 16) & 1u);  // RNE
  return (ushort_t)(r >> 16);
}
__device__ inline float bf2f(ushort_t u) {
  union { unsigned u; float f; } v; v.u = ((unsigned)u) << 16;
  return v.f;
}

__device__ inline void async16(const void* g, void* l) {
  __builtin_amdgcn_global_load_lds(
      (const __attribute__((address_space(1))) unsigned int*)g,
      (__attribute__((address_space(3))) unsigned int*)l, 16, 0, 0);
}

// LDS byte offset of a generic pointer into __shared__ space
__device__ inline unsigned ldsOff(const void* p) {
  return (unsigned)(unsigned long long)(const __attribute__((address_space(3))) char*)p;
}
// raw ds_read_b128 — invisible to SIInsertWaitcnts' LDS-DMA alias tracking
__device__ inline bf16x8 dsr128(unsigned byteOff) {
  bf16x8 r;
  asm volatile("ds_read_b128 %0, %1" : "=v"(r) : "v"(byteOff));
  return r;
}

// ---------------- prep: gate softmax (fp32) + feature bf16 cast, fused ----------------
__global__ void prep_kernel(const float* __restrict__ features, const float* __restrict__ Wg,
                            const float* __restrict__ bg, float* __restrict__ g2,
                            ushort_t* __restrict__ featbf) {
  const int fb = blockIdx.x;
  const int f = fb >> 12, b = fb & (B_ - 1);
  const int lane = threadIdx.x;
  const float* feat = features + ((size_t)f * B_ + b) * D_;
  const float* wg = Wg + (size_t)f * D_ * E_;
  const int d0 = lane * 8;
  float ff[8];
  *(float4*)&ff[0] = *(const float4*)&feat[d0];
  *(float4*)&ff[4] = *(const float4*)&feat[d0 + 4];
  ushort8_t u;
#pragma unroll
  for (int k = 0; k < 8; ++k) u[k] = f2bf(ff[k]);
  *(ushort8_t*)&featbf[((size_t)f * B_ + b) * D_ + d0] = u;

  float acc[E_] = {0.f, 0.f, 0.f, 0.f, 0.f, 0.f, 0.f, 0.f};
#pragma unroll
  for (int k = 0; k < 8; ++k) {
    const float fv = ff[k];
    const float4 w0 = ((const float4*)(wg + (size_t)(d0 + k) * E_))[0];
    const float4 w1 = ((const float4*)(wg + (size_t)(d0 + k) * E_))[1];
    acc[0] += fv * w0.x; acc[1] += fv * w0.y; acc[2] += fv * w0.z; acc[3] += fv * w0.w;
    acc[4] += fv * w1.x; acc[5] += fv * w1.y; acc[6] += fv * w1.z; acc[7] += fv * w1.w;
  }
#pragma unroll
  for (int off = 32; off >= 1; off >>= 1)
#pragma unroll
    for (int e = 0; e < E_; ++e) acc[e] += __shfl_xor(acc[e], off, 64);
  float lg[E_], mx = -1e30f;
#pragma unroll
  for (int e = 0; e < E_; ++e) { lg[e] = acc[e] + bg[f * E_ + e]; mx = fmaxf(mx, lg[e]); }
  float s = 0.f;
#pragma unroll
  for (int e = 0; e < E_; ++e) { lg[e] = __expf(lg[e] - mx); s += lg[e]; }
  const float inv = 1.f / (s * (float)F_);
  if (lane < E_) g2[((size_t)f * B_ + b) * E_ + lane] = lg[lane] * inv;
}

// ------------- batched transpose+cast: [R][C] fp32 -> [C][R] bf16 -------------
__global__ void transpose_cast_kernel(const float* __restrict__ in, ushort_t* __restrict__ out,
                                      int R, int C) {
  __shared__ float tile[64][65];
  const size_t zoff = (size_t)blockIdx.z * R * C;
  in += zoff; out += zoff;
  const int tx = threadIdx.x & 63, ty = threadIdx.x >> 6;
  const int r0 = blockIdx.y * 64, c0 = blockIdx.x * 64;
#pragma unroll
  for (int i = 0; i < 16; ++i) {
    const int r = ty + i * 4;
    tile[r][tx] = in[(size_t)(r0 + r) * C + c0 + tx];
  }
  __syncthreads();
#pragma unroll
  for (int i = 0; i < 16; ++i) {
    const int c = ty + i * 4;
    out[(size_t)(c0 + c) * R + r0 + tx] = f2bf(tile[tx][c]);
  }
}

// ================= GEMM engines: 128x128 tile, BK=32, 3-slot ring, 256 thr =================
// LDS slot (16 KB): A[128 rows][32 k] bytes 0..8191, B[128][32] bytes 8192..16383.
// 3 slots = 48 KB -> 3 blocks/CU. Epilogue overlays [128][136] bf16 (34816 B).
// Staging: thread t -> row rr=t>>2 (+64 for 2nd call), phys chunk t&3, source
// chunk (t&3)^FSW(rr); DMA dest linear (t*16B per 4KB region).
// Reads: phys chunk q^FSW(lr) (lane-constant) -> 8 lanes/bank-quad, conflict-free.
// Ring: step kt reads slot kt%3; barrier1; stage tile kt+3 into the same slot;
// vmcnt(8) (tile kt+1's 4 loads retired, kt+2/kt+3 in flight); barrier2.
// acc[i][j]: m = wm*64+i*16+lr, n = wn*64+j*16+q*4+{0..3}.

#define FSW(r) (((r) + ((r) >> 2)) & 3)

#define VM8 asm volatile("s_waitcnt vmcnt(8)" ::: "memory")
#define VM4 asm volatile("s_waitcnt vmcnt(4)" ::: "memory")
#define VM0 asm volatile("s_waitcnt vmcnt(0)" ::: "memory")
#define VMN ((void)0)

#define G1_STAGE(ktn, SLOT) { \
    ushort_t* s_ = &lds[(SLOT) * 8192]; \
    const ushort_t* a_ = aG + (ktn) * 32; \
    const ushort_t* b_ = bG + (ktn) * 32; \
    async16(a_,           s_ + t * 8); \
    async16(a_ + 64 * D_, s_ + 2048 + t * 8); \
    async16(b_,           s_ + 4096 + t * 8); \
    async16(b_ + 64 * D_, s_ + 6144 + t * 8); }

#define G2_STAGE(ktn, SLOT) { \
    ushort_t* s_ = &lds[(SLOT) * 8192]; \
    const ushort_t* a_ = HfA + (size_t)((ktn) >> 5) * ((size_t)B_ * H_) + aOff + ((ktn) & 31) * 32; \
    const ushort_t* b_ = w2A + (size_t)((ktn) >> 5) * ((size_t)O_ * H_) + bOff + ((ktn) & 31) * 32; \
    async16(a_,           s_ + t * 8); \
    async16(a_ + 64 * H_, s_ + 2048 + t * 8); \
    async16(b_,           s_ + 4096 + t * 8); \
    async16(b_ + 64 * H_, s_ + 6144 + t * 8); }

// One K-step: asm ds_reads -> lgkm wait -> 16 MFMA -> barrier1 -> stage -> vmcnt -> barrier2
#define GSTEP(kt, SLOT, STG, VMS, STAGEM) { \
    const unsigned sb = ldsB + (SLOT) * 16384u; \
    bf16x8 af[4], bfr[4]; \
    _Pragma("unroll") for (int i_ = 0; i_ < 4; ++i_) af[i_] = dsr128(sb + aRd + i_ * 1024u); \
    _Pragma("unroll") for (int j_ = 0; j_ < 4; ++j_) bfr[j_] = dsr128(sb + bRd + j_ * 1024u); \
    asm volatile("s_waitcnt lgkmcnt(0)" ::: "memory"); \
    __builtin_amdgcn_sched_barrier(0); \
    __builtin_amdgcn_s_setprio(1); \
    _Pragma("unroll") for (int i_ = 0; i_ < 4; ++i_) \
      _Pragma("unroll") for (int j_ = 0; j_ < 4; ++j_) \
        acc[i_][j_] = __builtin_amdgcn_mfma_f32_16x16x32_bf16(bfr[j_], af[i_], acc[i_][j_], 0, 0, 0); \
    __builtin_amdgcn_s_setprio(0); \
    __builtin_amdgcn_sched_barrier(0); \
    __builtin_amdgcn_s_barrier(); \
    if (STG) { STAGEM((kt) + 3, SLOT); } \
    VMS; \
    __builtin_amdgcn_s_barrier(); \
    __builtin_amdgcn_sched_barrier(0); }

// ---------------- GEMM1: Hf[e][m][n] = bf16(g2 * relu(feat @ W1t + b1)) ----------------
__global__ __launch_bounds__(256, 3) void gemm1_kernel(
    const ushort_t* __restrict__ featbf, const ushort_t* __restrict__ w1t,
    const float* __restrict__ b1, const float* __restrict__ g2,
    ushort_t* __restrict__ Hf, int f) {
  __shared__ __align__(16) ushort_t lds[24576];  // 49152 B
  const int id = blockIdx.x;
  const int e = id & 7;
  const int s = id >> 3;
  const int n0 = (s & 7) * 128;   // h
  const int m0 = (s >> 3) * 128;  // b
  const ushort_t* A  = featbf + (size_t)f * B_ * D_;
  const ushort_t* Bp = w1t + ((size_t)f * E_ + e) * (size_t)H_ * D_;
  const float* b1e = b1 + ((size_t)f * E_ + e) * H_;
  const float* g2f = g2 + (size_t)f * B_ * E_;
  ushort_t* HfE = Hf + (size_t)e * B_ * H_;

  const int t = threadIdx.x, lane = t & 63, w = t >> 6;
  const int wm = w & 1, wn = w >> 1;
  const int lr = lane & 15, q = lane >> 4;
  const unsigned ldsB = ldsOff(lds);
  const unsigned caBy = (unsigned)((q ^ FSW(lr)) * 16);
  const unsigned aRd = (unsigned)((wm * 64 + lr) * 64) + caBy;
  const unsigned bRd = 8192u + (unsigned)((wn * 64 + lr) * 64) + caBy;

  const int rr = t >> 2;                 // 0..63
  const int cc = (t & 3) ^ FSW(rr);
  const ushort_t* aG = A  + (size_t)(m0 + rr) * D_ + cc * 8;
  const ushort_t* bG = Bp + (size_t)(n0 + rr) * D_ + cc * 8;

  f32x4 acc[4][4];
#pragma unroll
  for (int i = 0; i < 4; ++i)
#pragma unroll
    for (int j = 0; j < 4; ++j) acc[i][j] = (f32x4){0.f, 0.f, 0.f, 0.f};

  // prologue: stage tiles 0,1,2 into slots 0,1,2 (12 loads); tile0 ready at <=8
  G1_STAGE(0, 0); G1_STAGE(1, 1); G1_STAGE(2, 2);
  VM8;
  __builtin_amdgcn_s_barrier();
  __builtin_amdgcn_sched_barrier(0);

  // 16 K-steps (D=512/32). Steps 0..12 stage kt+3; tail vmcnt 8->4->0.
  for (int b = 0; b < 12; b += 3) {
    GSTEP(b + 0, 0, 1, VM8, G1_STAGE);
    GSTEP(b + 1, 1, 1, VM8, G1_STAGE);
    GSTEP(b + 2, 2, 1, VM8, G1_STAGE);
  }
  GSTEP(12, 0, 1, VM8, G1_STAGE);  // stages tile 15 -> slot 0
  GSTEP(13, 1, 0, VM4, G1_STAGE);
  GSTEP(14, 2, 0, VM0, G1_STAGE);
  GSTEP(15, 0, 0, VMN, G1_STAGE);

  // epilogue: bias+relu+gate -> LDS [128][136] -> coalesced stores
  ushort_t* cb = lds;
#pragma unroll
  for (int i = 0; i < 4; ++i) {
    const int ml = wm * 64 + i * 16 + lr;
    const float gv = g2f[(size_t)(m0 + ml) * E_ + e];
#pragma unroll
    for (int j = 0; j < 4; ++j) {
      const int nl = wn * 64 + j * 16 + q * 4;
      const float4 bb = *(const float4*)&b1e[n0 + nl];
      ushort4 o;
      o.x = f2bf(fmaxf(acc[i][j][0] + bb.x, 0.f) * gv);
      o.y = f2bf(fmaxf(acc[i][j][1] + bb.y, 0.f) * gv);
      o.z = f2bf(fmaxf(acc[i][j][2] + bb.z, 0.f) * gv);
      o.w = f2bf(fmaxf(acc[i][j][3] + bb.w, 0.f) * gv);
      *(ushort4*)&cb[ml * 136 + nl] = o;
    }
  }
  __syncthreads();
  const int row = t >> 1, half = t & 1;
  const ushort_t* src = &cb[row * 136 + half * 64];
  ushort_t* dst = HfE + (size_t)(m0 + row) * H_ + n0 + half * 64;
#pragma unroll
  for (int c = 0; c < 8; ++c)
    *(ushort8_t*)(dst + c * 8) = *(const ushort8_t*)(src + c * 8);
}

// ---------------- GEMM2: part[f][grp] = sum_{e in grp} Hf_e @ W2t_e + g*b2 ----------------
__global__ __launch_bounds__(256, 3) void gemm2_kernel(
    const ushort_t* __restrict__ Hf, const ushort_t* __restrict__ w2t,
    const float* __restrict__ b2, const float* __restrict__ g2,
    ushort_t* __restrict__ part, int f) {
  __shared__ __align__(16) ushort_t lds[24576];  // 49152 B
  const int id = blockIdx.x;
  const int grp = id & 3;
  const int s = id >> 2;
  const int n0 = (s & 3) * 128;   // o
  const int m0 = (s >> 2) * 128;  // b
  const int e0 = grp * 2;
  const ushort_t* HfA = Hf + (size_t)e0 * B_ * H_;
  const ushort_t* w2A = w2t + ((size_t)f * E_ + e0) * (size_t)O_ * H_;
  const float* g2f = g2 + (size_t)f * B_ * E_;

  const int t = threadIdx.x, lane = t & 63, w = t >> 6;
  const int wm = w & 1, wn = w >> 1;
  const int lr = lane & 15, q = lane >> 4;
  const unsigned ldsB = ldsOff(lds);
  const unsigned caBy = (unsigned)((q ^ FSW(lr)) * 16);
  const unsigned aRd = (unsigned)((wm * 64 + lr) * 64) + caBy;
  const unsigned bRd = 8192u + (unsigned)((wn * 64 + lr) * 64) + caBy;

  const int rr = t >> 2;
  const int cc = (t & 3) ^ FSW(rr);
  const size_t aOff = (size_t)(m0 + rr) * H_ + cc * 8;
  const size_t bOff = (size_t)(n0 + rr) * H_ + cc * 8;

  f32x4 acc[4][4];
#pragma unroll
  for (int i = 0; i < 4; ++i)
#pragma unroll
    for (int j = 0; j < 4; ++j) acc[i][j] = (f32x4){0.f, 0.f, 0.f, 0.f};

  G2_STAGE(0, 0); G2_STAGE(1, 1); G2_STAGE(2, 2);
  VM8;
  __builtin_amdgcn_s_barrier();
  __builtin_amdgcn_sched_barrier(0);

  // 64 K-steps (2 experts x H/32). Steps 0..60 stage kt+3; tail vmcnt 8->4->0.
  for (int b = 0; b < 60; b += 3) {
    GSTEP(b + 0, 0, 1, VM8, G2_STAGE);
    GSTEP(b + 1, 1, 1, VM8, G2_STAGE);
    GSTEP(b + 2, 2, 1, VM8, G2_STAGE);
  }
  GSTEP(60, 0, 1, VM8, G2_STAGE);  // stages tile 63 -> slot 0
  GSTEP(61, 1, 0, VM4, G2_STAGE);
  GSTEP(62, 2, 0, VM0, G2_STAGE);
  GSTEP(63, 0, 0, VMN, G2_STAGE);

  // epilogue: acc + g*b2 -> LDS [128][136] -> coalesced stores
  ushort_t* cb = lds;
  const float* b2e0 = b2 + ((size_t)f * E_ + e0) * O_;
  const float* b2e1 = b2e0 + O_;
#pragma unroll
  for (int i = 0; i < 4; ++i) {
    const int ml = wm * 64 + i * 16 + lr;
    const float gv0 = g2f[(size_t)(m0 + ml) * E_ + e0];
    const float gv1 = g2f[(size_t)(m0 + ml) * E_ + e0 + 1];
#pragma unroll
    for (int j = 0; j < 4; ++j) {
      const int nl = wn * 64 + j * 16 + q * 4;
      const int n = n0 + nl;
      const float4 c0 = *(const float4*)&b2e0[n];
      const float4 c1 = *(const float4*)&b2e1[n];
      ushort4 o;
      o.x = f2bf(acc[i][j][0] + gv0 * c0.x + gv1 * c1.x);
      o.y = f2bf(acc[i][j][1] + gv0 * c0.y + gv1 * c1.y);
      o.z = f2bf(acc[i][j][2] + gv0 * c0.z + gv1 * c1.z);
      o.w = f2bf(acc[i][j][3] + gv0 * c0.w + gv1 * c1.w);
      *(ushort4*)&cb[ml * 136 + nl] = o;
    }
  }
  __syncthreads();
  const int row = t >> 1, half = t & 1;
  const ushort_t* src = &cb[row * 136 + half * 64];
  ushort_t* dst = part + (size_t)(f * 4 + grp) * (B_ * O_) + (size_t)(m0 + row) * O_ + n0 + half * 64;
#pragma unroll
  for (int c = 0; c < 8; ++c)
    *(ushort8_t*)(dst + c * 8) = *(const ushort8_t*)(src + c * 8);
}

// ---------------- final reduce: out = sum over 16 bf16 slabs ----------------
__global__ void reduce_kernel(const ushort_t* __restrict__ part, float* __restrict__ out) {
  const size_t p = ((size_t)blockIdx.x * 256 + threadIdx.x) * 8;
  float s[8] = {0.f, 0.f, 0.f, 0.f, 0.f, 0.f, 0.f, 0.f};
#pragma unroll
  for (int k = 0; k < F_ * 4; ++k) {
    const ushort8_t u = *(const ushort8_t*)&part[(size_t)k * (B_ * O_) + p];
#pragma unroll
    for (int j = 0; j < 8; ++j) s[j] += bf2f(u[j]);
  }
  float4 o0 = {s[0], s[1], s[2], s[3]}, o1 = {s[4], s[5], s[6], s[7]};
  *(float4*)&out[p] = o0;
  *(float4*)&out[p + 4] = o1;
}

extern "C" void kernel_launch(void* const* d_in, const int* in_sizes, int n_in,
                              void* d_out, int out_size, void* d_ws, size_t ws_size,
                              hipStream_t stream) {
  const float* features = (const float*)d_in[0];
  const float* W1 = (const float*)d_in[1];
  const float* b1 = (const float*)d_in[2];
  const float* W2 = (const float*)d_in[3];
  const float* b2 = (const float*)d_in[4];
  const float* Wg = (const float*)d_in[5];
  const float* bg = (const float*)d_in[6];
  float* out = (float*)d_out;

  char* ws = (char*)d_ws;
  ushort_t* featbf = (ushort_t*)ws;                  // 16 MB   [F][B][D]
  ushort_t* w1t    = (ushort_t*)(ws + 16777216);     // 32 MB   [F][E][H][D]
  ushort_t* w2t    = (ushort_t*)(ws + 50331648);     // 32 MB   [F][E][O][H]
  float*    g2     = (float*)(ws + 83886080);        // 0.5 MB  [F][B][E]
  ushort_t* Hf     = (ushort_t*)(ws + 84410368);     // 64 MB   [E][B][H] (per-f)
  ushort_t* part   = (ushort_t*)(ws + 151519232);    // 64 MB   [F*4][B][O] bf16

  prep_kernel<<<F_ * B_, 64, 0, stream>>>(features, Wg, bg, g2, featbf);
  transpose_cast_kernel<<<dim3(H_ / 64, D_ / 64, F_ * E_), 256, 0, stream>>>(W1, w1t, D_, H_);
  transpose_cast_kernel<<<dim3(O_ / 64, H_ / 64, F_ * E_), 256, 0, stream>>>(W2, w2t, H_, O_);

  for (int f = 0; f < F_; ++f) {
    gemm1_kernel<<<2048, 256, 0, stream>>>(featbf, w1t, b1, g2, Hf, f);
    gemm2_kernel<<<512, 256, 0, stream>>>(Hf, w2t, b2, g2, part, f);
  }
  reduce_kernel<<<B_ * O_ / 8 / 256, 256, 0, stream>>>(part, out);
}

// Round 4
// 621.573 us; speedup vs baseline: 1.0754x; 1.0584x over previous
//
#include <hip/hip_runtime.h>

// MultiFeatureMOE: F=4, E=8, B=4096, D=512, H=1024, O=512.
// Round 11: short-K overhead amortization. R10 showed two different K-loop sync
// structures both land at ~505 TF with all pipes idle -> per-block fixed costs
// (prologue drain + epilogue + syncs) over only 8-16 K-steps are the limiter,
// not the loop schedule. Fix: 4x more K-work per block.
//  - gemm1: 256x256 tile, 8 waves (wave 128x64, 64 MFMA / 24 ds_reads per
//    K-tile), BK=64 (128B LDS rows + proven chunk^(row&7) swizzle, ~0
//    conflicts), 2-slot dbuf (128KB), stage-at-top -> vmcnt(0) ~460cy later,
//    ONE barrier per K-tile. Grid 512/f.
//  - gemm2: 128x256 tile, 8 waves (wave 64x64), BK=64, 3-slot ring with
//    COUNTED vmcnt(6) (lead 2 K-tiles, never 0 till tail), 144KB LDS,
//    K=2048 (2 experts) = 32 K-tiles. Grid 256/f = 1 block/CU.
//  - K-loop LDS reads stay inline-asm ds_read_b128 + lgkmcnt(0)+sched_barrier
//    (rule 18; machinery correctness-verified in R10).

#define F_ 4
#define E_ 8
#define B_ 4096
#define D_ 512
#define H_ 1024
#define O_ 512

typedef unsigned short ushort_t;
typedef __bf16 bf16x8 __attribute__((ext_vector_type(8)));
typedef float f32x4 __attribute__((ext_vector_type(4)));
typedef unsigned short ushort8_t __attribute__((ext_vector_type(8)));

__device__ inline ushort_t f2bf(float f) {
  union { float f; unsigned u; } v; v.f = f;
  unsigned r = v.u + 0x7FFFu + ((v.u >> 16) & 1u);  // RNE
  return (ushort_t)(r >> 16);
}
__device__ inline float bf2f(ushort_t u) {
  union { unsigned u; float f; } v; v.u = ((unsigned)u) << 16;
  return v.f;
}

__device__ inline void async16(const void* g, void* l) {
  __builtin_amdgcn_global_load_lds(
      (const __attribute__((address_space(1))) unsigned int*)g,
      (__attribute__((address_space(3))) unsigned int*)l, 16, 0, 0);
}

__device__ inline unsigned ldsOff(const void* p) {
  return (unsigned)(unsigned long long)(const __attribute__((address_space(3))) char*)p;
}
// raw ds_read_b128 — invisible to SIInsertWaitcnts' LDS-DMA alias tracking
__device__ inline bf16x8 dsr128(unsigned byteOff) {
  bf16x8 r;
  asm volatile("ds_read_b128 %0, %1" : "=v"(r) : "v"(byteOff));
  return r;
}

#define VM0 asm volatile("s_waitcnt vmcnt(0)" ::: "memory")
#define VM6 asm volatile("s_waitcnt vmcnt(6)" ::: "memory")
#define BAR { __builtin_amdgcn_sched_barrier(0); __builtin_amdgcn_s_barrier(); \
              __builtin_amdgcn_sched_barrier(0); }

// ---------------- prep: gate softmax (fp32) + feature bf16 cast, fused ----------------
__global__ void prep_kernel(const float* __restrict__ features, const float* __restrict__ Wg,
                            const float* __restrict__ bg, float* __restrict__ g2,
                            ushort_t* __restrict__ featbf) {
  const int fb = blockIdx.x;
  const int f = fb >> 12, b = fb & (B_ - 1);
  const int lane = threadIdx.x;
  const float* feat = features + ((size_t)f * B_ + b) * D_;
  const float* wg = Wg + (size_t)f * D_ * E_;
  const int d0 = lane * 8;
  float ff[8];
  *(float4*)&ff[0] = *(const float4*)&feat[d0];
  *(float4*)&ff[4] = *(const float4*)&feat[d0 + 4];
  ushort8_t u;
#pragma unroll
  for (int k = 0; k < 8; ++k) u[k] = f2bf(ff[k]);
  *(ushort8_t*)&featbf[((size_t)f * B_ + b) * D_ + d0] = u;

  float acc[E_] = {0.f, 0.f, 0.f, 0.f, 0.f, 0.f, 0.f, 0.f};
#pragma unroll
  for (int k = 0; k < 8; ++k) {
    const float fv = ff[k];
    const float4 w0 = ((const float4*)(wg + (size_t)(d0 + k) * E_))[0];
    const float4 w1 = ((const float4*)(wg + (size_t)(d0 + k) * E_))[1];
    acc[0] += fv * w0.x; acc[1] += fv * w0.y; acc[2] += fv * w0.z; acc[3] += fv * w0.w;
    acc[4] += fv * w1.x; acc[5] += fv * w1.y; acc[6] += fv * w1.z; acc[7] += fv * w1.w;
  }
#pragma unroll
  for (int off = 32; off >= 1; off >>= 1)
#pragma unroll
    for (int e = 0; e < E_; ++e) acc[e] += __shfl_xor(acc[e], off, 64);
  float lg[E_], mx = -1e30f;
#pragma unroll
  for (int e = 0; e < E_; ++e) { lg[e] = acc[e] + bg[f * E_ + e]; mx = fmaxf(mx, lg[e]); }
  float s = 0.f;
#pragma unroll
  for (int e = 0; e < E_; ++e) { lg[e] = __expf(lg[e] - mx); s += lg[e]; }
  const float inv = 1.f / (s * (float)F_);
  if (lane < E_) g2[((size_t)f * B_ + b) * E_ + lane] = lg[lane] * inv;
}

// ------------- batched transpose+cast: [R][C] fp32 -> [C][R] bf16 -------------
__global__ void transpose_cast_kernel(const float* __restrict__ in, ushort_t* __restrict__ out,
                                      int R, int C) {
  __shared__ float tile[64][65];
  const size_t zoff = (size_t)blockIdx.z * R * C;
  in += zoff; out += zoff;
  const int tx = threadIdx.x & 63, ty = threadIdx.x >> 6;
  const int r0 = blockIdx.y * 64, c0 = blockIdx.x * 64;
#pragma unroll
  for (int i = 0; i < 16; ++i) {
    const int r = ty + i * 4;
    tile[r][tx] = in[(size_t)(r0 + r) * C + c0 + tx];
  }
  __syncthreads();
#pragma unroll
  for (int i = 0; i < 16; ++i) {
    const int c = ty + i * 4;
    out[(size_t)(c0 + c) * R + r0 + tx] = f2bf(tile[tx][c]);
  }
}

// ============== GEMM1: 256x256 tile, BK=64, 2-slot dbuf, 512 thr (8 waves) ==============
// LDS slot (64KB): A[256 rows][64k = 128B] @ 0, B[256][64] @ 32768B. 2 slots = 128KB.
// Rows are 128B; store phys chunk p holds source chunk p^(row&7)  (proven ~0-conflict).
// Staging: thread t -> rows (t>>3)+p*64 (p=0..3), phys chunk t&7, linear DMA dest.
// Reads (wave 128x64): af[8] rows wm*128+i*16+lr, bfr[4] rows wn*64+j*16+lr,
// phys chunk (kh*4+q)^(lr&7). 64 MFMA / 24 ds_reads per K-tile.
// acc[i][j]: m = wm*128+i*16+lr, n = wn*64+j*16+q*4+{0..3}.

#define G1_STAGE(ktn, c) { \
    ushort_t* s_ = &lds[(c) * 32768]; \
    const ushort_t* a_ = aG + (ktn) * 64; \
    const ushort_t* b_ = bG + (ktn) * 64; \
    _Pragma("unroll") for (int p = 0; p < 4; ++p) { \
      async16(a_ + (size_t)p * (64 * D_), s_ + p * 4096 + t * 8); \
      async16(b_ + (size_t)p * (64 * D_), s_ + 16384 + p * 4096 + t * 8); } }

#define G1_PHASE(sb, kh) { \
    bf16x8 af[8], bfr[4]; \
    const unsigned cx = (unsigned)((((kh) * 4 + q) ^ (lr & 7)) * 16); \
    _Pragma("unroll") for (int i_ = 0; i_ < 8; ++i_) \
      af[i_] = dsr128((sb) + (unsigned)((wm * 128 + i_ * 16 + lr) * 128) + cx); \
    _Pragma("unroll") for (int j_ = 0; j_ < 4; ++j_) \
      bfr[j_] = dsr128((sb) + 32768u + (unsigned)((wn * 64 + j_ * 16 + lr) * 128) + cx); \
    asm volatile("s_waitcnt lgkmcnt(0)" ::: "memory"); \
    __builtin_amdgcn_sched_barrier(0); \
    __builtin_amdgcn_s_setprio(1); \
    _Pragma("unroll") for (int i_ = 0; i_ < 8; ++i_) \
      _Pragma("unroll") for (int j_ = 0; j_ < 4; ++j_) \
        acc[i_][j_] = __builtin_amdgcn_mfma_f32_16x16x32_bf16(bfr[j_], af[i_], acc[i_][j_], 0, 0, 0); \
    __builtin_amdgcn_s_setprio(0); \
    __builtin_amdgcn_sched_barrier(0); }

#define G1_ITER(kt, c) { \
    const unsigned sb = ldsB + (c) * 65536u; \
    G1_STAGE((kt) + 1, (c) ^ 1); \
    G1_PHASE(sb, 0); \
    G1_PHASE(sb, 1); \
    VM0; BAR; }

__global__ __launch_bounds__(512, 2) void gemm1_kernel(
    const ushort_t* __restrict__ featbf, const ushort_t* __restrict__ w1t,
    const float* __restrict__ b1, const float* __restrict__ g2,
    ushort_t* __restrict__ Hf, int f) {
  __shared__ __align__(16) ushort_t lds[65536];  // 128 KB
  const int id = blockIdx.x;
  const int e = id & 7;
  const int s = id >> 3;          // 0..63
  const int n0 = (s & 3) * 256;   // h (4 tiles)
  const int m0 = (s >> 2) * 256;  // b (16 tiles)
  const ushort_t* A  = featbf + (size_t)f * B_ * D_;
  const ushort_t* Bp = w1t + ((size_t)f * E_ + e) * (size_t)H_ * D_;
  const float* b1e = b1 + ((size_t)f * E_ + e) * H_;
  const float* g2f = g2 + (size_t)f * B_ * E_;
  ushort_t* HfE = Hf + (size_t)e * B_ * H_;

  const int t = threadIdx.x, lane = t & 63, w = t >> 6;
  const int wm = w >> 2, wn = w & 3;        // wm 0..1, wn 0..3
  const int lr = lane & 15, q = lane >> 4;  // q 0..3
  const unsigned ldsB = ldsOff(lds);

  const int rr = t >> 3;                    // 0..63
  const int cc = (t & 7) ^ (rr & 7);        // staging source chunk
  const ushort_t* aG = A  + (size_t)(m0 + rr) * D_ + cc * 8;
  const ushort_t* bG = Bp + (size_t)(n0 + rr) * D_ + cc * 8;

  f32x4 acc[8][4];
#pragma unroll
  for (int i = 0; i < 8; ++i)
#pragma unroll
    for (int j = 0; j < 4; ++j) acc[i][j] = (f32x4){0.f, 0.f, 0.f, 0.f};

  // prologue: stage tile 0 into slot 0
  G1_STAGE(0, 0);
  VM0; BAR;

  // 8 K-tiles (D=512/64); tile kt reads slot kt&1, stages kt+1 into the other.
  G1_ITER(0, 0); G1_ITER(1, 1);
  G1_ITER(2, 0); G1_ITER(3, 1);
  G1_ITER(4, 0); G1_ITER(5, 1);
  G1_ITER(6, 0);                       // stages tile 7 -> slot 1
  { const unsigned sb = ldsB + 65536u; // kt = 7, no stage, no trailing sync
    G1_PHASE(sb, 0); G1_PHASE(sb, 1); }

  // epilogue: bias+relu+gate -> LDS [128][264] per M-half -> coalesced stores
  __syncthreads();
  ushort_t* cb = lds;
#pragma unroll
  for (int mh = 0; mh < 2; ++mh) {
    if (wm == mh) {
#pragma unroll
      for (int i = 0; i < 8; ++i) {
        const int rl = i * 16 + lr;  // 0..127
        const float gv = g2f[(size_t)(m0 + mh * 128 + rl) * E_ + e];
#pragma unroll
        for (int j = 0; j < 4; ++j) {
          const int nl = wn * 64 + j * 16 + q * 4;
          const float4 bb = *(const float4*)&b1e[n0 + nl];
          ushort4 o;
          o.x = f2bf(fmaxf(acc[i][j][0] + bb.x, 0.f) * gv);
          o.y = f2bf(fmaxf(acc[i][j][1] + bb.y, 0.f) * gv);
          o.z = f2bf(fmaxf(acc[i][j][2] + bb.z, 0.f) * gv);
          o.w = f2bf(fmaxf(acc[i][j][3] + bb.w, 0.f) * gv);
          *(ushort4*)&cb[rl * 264 + nl] = o;
        }
      }
    }
    __syncthreads();
    const int row = t >> 2, seg = t & 3;   // 128 rows x 4 segs of 128B
    const ushort_t* src = &cb[row * 264 + seg * 64];
    ushort_t* dst = HfE + (size_t)(m0 + mh * 128 + row) * H_ + n0 + seg * 64;
#pragma unroll
    for (int c2 = 0; c2 < 8; ++c2)
      *(ushort8_t*)(dst + c2 * 8) = *(const ushort8_t*)(src + c2 * 8);
    __syncthreads();
  }
}

// ============ GEMM2: 128x256 tile, BK=64, 3-slot ring (counted vmcnt), 512 thr ============
// LDS slot (48KB): A[128][64] @ 0 (16KB), B[256][64] @ 16384B (32KB). 3 slots = 144KB.
// 2 experts per block: K = 2048 -> 32 K-tiles. Ring: read kt%3, stage kt+2 at top,
// vmcnt(6) at tile end (tile kt+1's 6 loads retired, kt+2's 6 in flight). Lead = 2 tiles.
// Waves 2Mx4N -> wave 64x64: af[4] rows wm*64+i*16+lr, bfr[4] rows wn*64+j*16+lr.

#define G2_STAGE(ktn, c) { \
    ushort_t* s_ = &lds2[(c) * 24576]; \
    const ushort_t* a_ = Hf + (size_t)(e0 + ((ktn) >> 4)) * ((size_t)B_ * H_) + aOff + ((ktn) & 15) * 64; \
    const ushort_t* b_ = w2tF + (size_t)(e0 + ((ktn) >> 4)) * ((size_t)O_ * H_) + bOff + ((ktn) & 15) * 64; \
    _Pragma("unroll") for (int p = 0; p < 2; ++p) \
      async16(a_ + (size_t)p * (64 * H_), s_ + p * 4096 + t * 8); \
    _Pragma("unroll") for (int p = 0; p < 4; ++p) \
      async16(b_ + (size_t)p * (64 * H_), s_ + 8192 + p * 4096 + t * 8); }

#define G2_PHASE(sb, kh) { \
    bf16x8 af[4], bfr[4]; \
    const unsigned cx = (unsigned)((((kh) * 4 + q) ^ (lr & 7)) * 16); \
    _Pragma("unroll") for (int i_ = 0; i_ < 4; ++i_) \
      af[i_] = dsr128((sb) + (unsigned)((wm * 64 + i_ * 16 + lr) * 128) + cx); \
    _Pragma("unroll") for (int j_ = 0; j_ < 4; ++j_) \
      bfr[j_] = dsr128((sb) + 16384u + (unsigned)((wn * 64 + j_ * 16 + lr) * 128) + cx); \
    asm volatile("s_waitcnt lgkmcnt(0)" ::: "memory"); \
    __builtin_amdgcn_sched_barrier(0); \
    __builtin_amdgcn_s_setprio(1); \
    _Pragma("unroll") for (int i_ = 0; i_ < 4; ++i_) \
      _Pragma("unroll") for (int j_ = 0; j_ < 4; ++j_) \
        acc[i_][j_] = __builtin_amdgcn_mfma_f32_16x16x32_bf16(bfr[j_], af[i_], acc[i_][j_], 0, 0, 0); \
    __builtin_amdgcn_s_setprio(0); \
    __builtin_amdgcn_sched_barrier(0); }

#define G2_ITER(kt, c, cn) { \
    const unsigned sb = ldsB + (c) * 49152u; \
    G2_STAGE((kt) + 2, cn); \
    G2_PHASE(sb, 0); \
    G2_PHASE(sb, 1); \
    VM6; BAR; }

__global__ __launch_bounds__(512, 2) void gemm2_kernel(
    const ushort_t* __restrict__ Hf, const ushort_t* __restrict__ w2t,
    const float* __restrict__ b2, const float* __restrict__ g2,
    ushort_t* __restrict__ part, int f) {
  __shared__ __align__(16) ushort_t lds2[73728];  // 144 KB
  const int id = blockIdx.x;      // 0..255
  const int grp = id & 3;
  const int s = id >> 2;          // 0..63
  const int n0 = (s & 1) * 256;   // o (2 tiles)
  const int m0 = (s >> 1) * 128;  // b (32 tiles)
  const int e0 = grp * 2;
  const ushort_t* w2tF = w2t + (size_t)f * E_ * O_ * H_;
  const float* g2f = g2 + (size_t)f * B_ * E_;

  const int t = threadIdx.x, lane = t & 63, w = t >> 6;
  const int wm = w >> 2, wn = w & 3;        // wm 0..1, wn 0..3
  const int lr = lane & 15, q = lane >> 4;
  const unsigned ldsB = ldsOff(lds2);

  const int rr = t >> 3;                    // 0..63
  const int cc = (t & 7) ^ (rr & 7);
  const size_t aOff = (size_t)(m0 + rr) * H_ + cc * 8;
  const size_t bOff = (size_t)(n0 + rr) * H_ + cc * 8;

  f32x4 acc[4][4];
#pragma unroll
  for (int i = 0; i < 4; ++i)
#pragma unroll
    for (int j = 0; j < 4; ++j) acc[i][j] = (f32x4){0.f, 0.f, 0.f, 0.f};

  // prologue: stage tiles 0,1 (12 loads); tile0 ready when <=6 outstanding
  G2_STAGE(0, 0); G2_STAGE(1, 1);
  VM6; BAR;

  // 32 K-tiles. kt=0..29 stage kt+2 & vmcnt(6); kt=30 vmcnt(0); kt=31 bare.
  for (int b = 0; b < 30; b += 3) {
    G2_ITER(b + 0, 0, 2);
    G2_ITER(b + 1, 1, 0);
    G2_ITER(b + 2, 2, 1);
  }
  { const unsigned sb = ldsB + 0u;          // kt = 30 (30%3 == 0)
    G2_PHASE(sb, 0); G2_PHASE(sb, 1); VM0; BAR; }
  { const unsigned sb = ldsB + 49152u;      // kt = 31 (31%3 == 1)
    G2_PHASE(sb, 0); G2_PHASE(sb, 1); }

  // epilogue: acc + g0*b2e0 + g1*b2e1 -> LDS [128][264] -> coalesced stores
  __syncthreads();
  ushort_t* cb = lds2;
  const float* b2e0 = b2 + ((size_t)f * E_ + e0) * O_;
  const float* b2e1 = b2e0 + O_;
#pragma unroll
  for (int i = 0; i < 4; ++i) {
    const int ml = wm * 64 + i * 16 + lr;   // 0..127
    const float gv0 = g2f[(size_t)(m0 + ml) * E_ + e0];
    const float gv1 = g2f[(size_t)(m0 + ml) * E_ + e0 + 1];
#pragma unroll
    for (int j = 0; j < 4; ++j) {
      const int nl = wn * 64 + j * 16 + q * 4;  // 0..255
      const int n = n0 + nl;
      const float4 c0 = *(const float4*)&b2e0[n];
      const float4 c1 = *(const float4*)&b2e1[n];
      ushort4 o;
      o.x = f2bf(acc[i][j][0] + gv0 * c0.x + gv1 * c1.x);
      o.y = f2bf(acc[i][j][1] + gv0 * c0.y + gv1 * c1.y);
      o.z = f2bf(acc[i][j][2] + gv0 * c0.z + gv1 * c1.z);
      o.w = f2bf(acc[i][j][3] + gv0 * c0.w + gv1 * c1.w);
      *(ushort4*)&cb[ml * 264 + nl] = o;
    }
  }
  __syncthreads();
  const int row = t >> 2, seg = t & 3;       // 128 rows x 4 segs of 64 ushorts
  const ushort_t* src = &cb[row * 264 + seg * 64];
  ushort_t* dst = part + (size_t)(f * 4 + grp) * (B_ * O_) + (size_t)(m0 + row) * O_ + n0 + seg * 64;
#pragma unroll
  for (int c2 = 0; c2 < 8; ++c2)
    *(ushort8_t*)(dst + c2 * 8) = *(const ushort8_t*)(src + c2 * 8);
}

// ---------------- final reduce: out = sum over 16 bf16 slabs ----------------
__global__ void reduce_kernel(const ushort_t* __restrict__ part, float* __restrict__ out) {
  const size_t p = ((size_t)blockIdx.x * 256 + threadIdx.x) * 8;
  float s[8] = {0.f, 0.f, 0.f, 0.f, 0.f, 0.f, 0.f, 0.f};
#pragma unroll
  for (int k = 0; k < F_ * 4; ++k) {
    const ushort8_t u = *(const ushort8_t*)&part[(size_t)k * (B_ * O_) + p];
#pragma unroll
    for (int j = 0; j < 8; ++j) s[j] += bf2f(u[j]);
  }
  float4 o0 = {s[0], s[1], s[2], s[3]}, o1 = {s[4], s[5], s[6], s[7]};
  *(float4*)&out[p] = o0;
  *(float4*)&out[p + 4] = o1;
}

extern "C" void kernel_launch(void* const* d_in, const int* in_sizes, int n_in,
                              void* d_out, int out_size, void* d_ws, size_t ws_size,
                              hipStream_t stream) {
  const float* features = (const float*)d_in[0];
  const float* W1 = (const float*)d_in[1];
  const float* b1 = (const float*)d_in[2];
  const float* W2 = (const float*)d_in[3];
  const float* b2 = (const float*)d_in[4];
  const float* Wg = (const float*)d_in[5];
  const float* bg = (const float*)d_in[6];
  float* out = (float*)d_out;

  char* ws = (char*)d_ws;
  ushort_t* featbf = (ushort_t*)ws;                  // 16 MB   [F][B][D]
  ushort_t* w1t    = (ushort_t*)(ws + 16777216);     // 32 MB   [F][E][H][D]
  ushort_t* w2t    = (ushort_t*)(ws + 50331648);     // 32 MB   [F][E][O][H]
  float*    g2     = (float*)(ws + 83886080);        // 0.5 MB  [F][B][E]
  ushort_t* Hf     = (ushort_t*)(ws + 84410368);     // 64 MB   [E][B][H] (per-f)
  ushort_t* part   = (ushort_t*)(ws + 151519232);    // 64 MB   [F*4][B][O] bf16

  prep_kernel<<<F_ * B_, 64, 0, stream>>>(features, Wg, bg, g2, featbf);
  transpose_cast_kernel<<<dim3(H_ / 64, D_ / 64, F_ * E_), 256, 0, stream>>>(W1, w1t, D_, H_);
  transpose_cast_kernel<<<dim3(O_ / 64, H_ / 64, F_ * E_), 256, 0, stream>>>(W2, w2t, H_, O_);

  for (int f = 0; f < F_; ++f) {
    gemm1_kernel<<<512, 512, 0, stream>>>(featbf, w1t, b1, g2, Hf, f);
    gemm2_kernel<<<256, 512, 0, stream>>>(Hf, w2t, b2, g2, part, f);
  }
  reduce_kernel<<<B_ * O_ / 8 / 256, 256, 0, stream>>>(part, out);
}